// Round 11
// baseline (257.316 us; speedup 1.0000x reference)
//
#include <hip/hip_runtime.h>
#include <cstdint>

#define T_DIM 4
#define B_DIM 8
#define C_DIM 512
#define N_DIM 576
#define CV_DIM 2048
#define TB_DIM 32
#define NW 9              // u64 words per row of N=576

typedef unsigned long long u64;
typedef unsigned char u8;
typedef uint32_t u32;
typedef _Float16 h16;
typedef __attribute__((ext_vector_type(8))) _Float16 f16x8;
typedef __attribute__((ext_vector_type(16))) float f32x16;

// async global->LDS, 16B per lane; lds ptr must be wave-uniform chunk base
__device__ __forceinline__ void gload16(const void* gp, void* lp) {
    __builtin_amdgcn_global_load_lds(
        (const __attribute__((address_space(1))) void*)gp,
        (__attribute__((address_space(3))) void*)lp, 16, 0, 0);
}

// ---------------- Stage 1: LIF over (x + pos) -> dense f16 spikes, TRANSPOSED [t][b][n][c] ----------------
// c-granules (8 h16 = 16B) XOR-swizzled by (n&3) within each 32-c chunk (matches gemm_qkv BK=32 frag reads).
__global__ __launch_bounds__(256) void lif_x_T(const float* __restrict__ x,
                                               const float* __restrict__ pos,
                                               h16* __restrict__ sxT) {
    const int ct = blockIdx.x, nt = blockIdx.y, b = blockIdx.z;
    const int c0 = ct * 64, n0 = nt * 64;
    __shared__ h16 T[64][64];              // [n][c] 8 KB
    const int tid = threadIdx.x;
    const int n_l = tid & 63, cg = tid >> 6;
    const int row = tid >> 2, q = tid & 3;

    float pv[16], mem[16], spk[16];
    #pragma unroll
    for (int ii = 0; ii < 16; ++ii) {
        pv[ii] = pos[(c0 + cg * 16 + ii) * N_DIM + n0 + n_l];
        mem[ii] = 0.f; spk[ii] = 0.f;
    }
    for (int t = 0; t < T_DIM; ++t) {
        #pragma unroll
        for (int ii = 0; ii < 16; ++ii) {
            float xt = x[((size_t)(t * B_DIM + b) * C_DIM + c0 + cg * 16 + ii) * N_DIM + n0 + n_l] + pv[ii];
            mem[ii] = mem[ii] * 0.25f * (1.f - spk[ii]) + xt;
            spk[ii] = (mem[ii] > 0.5f) ? 1.f : 0.f;
            T[n_l][cg * 16 + ii] = (h16)spk[ii];
        }
        __syncthreads();
        {
            h16* dst = sxT + ((size_t)(t * B_DIM + b) * N_DIM + n0 + row) * C_DIM + c0;
            const int f = row & 3;     // (n0+row)&3 == row&3
            #pragma unroll
            for (int e = 0; e < 2; ++e) {
                int gl = q + e * 4;                         // logical granule 0..7
                uint4 v = *(const uint4*)&T[row][gl * 8];
                int slot = (gl & ~3) | ((gl & 3) ^ f);      // swizzle within 4-granule chunk
                *(uint4*)(dst + slot * 8) = v;
            }
        }
        __syncthreads();
    }
}

// ---------------- Weight split: W*4096 = h1 + h2, granule-swizzled (&3) layout ----------------
__global__ __launch_bounds__(256) void split_qkv(const float* __restrict__ q_w,
                                                 const float* __restrict__ k_w,
                                                 const float* __restrict__ v_w,
                                                 h16* __restrict__ wp) {   // [2][3072][512]
    int i = blockIdx.x * 256 + threadIdx.x;
    int row = i >> 6;
    int g = i & 63;
    int g8 = g * 8;
    const float* src = (row < 512) ? q_w + (size_t)row * 512
                     : (row < 1024) ? k_w + (size_t)(row - 512) * 512
                                    : v_w + (size_t)(row - 1024) * 512;
    float4 a = *(const float4*)(src + g8);
    float4 bq = *(const float4*)(src + g8 + 4);
    float v[8] = {a.x, a.y, a.z, a.w, bq.x, bq.y, bq.z, bq.w};
    f16x8 vh, vl;
    #pragma unroll
    for (int j = 0; j < 8; ++j) {
        float w = v[j] * 4096.f;
        h16 h1 = (h16)w;
        vh[j] = h1;
        vl[j] = (h16)(w - (float)h1);
    }
    int permcol = ((g & ~3) + ((g & 3) ^ (row & 3))) * 8;   // swizzle within 32-c chunk
    *(f16x8*)(wp + (size_t)row * 512 + permcol) = vh;
    *(f16x8*)(wp + (size_t)3072 * 512 + (size_t)row * 512 + permcol) = vl;
}

// p-weights: hi plane only, &7 swizzle (gemm_p stays BK=64)
__global__ __launch_bounds__(256) void split_p(const float* __restrict__ p_w,
                                               h16* __restrict__ wp) {     // [512][2048] (hi only)
    int i = blockIdx.x * 256 + threadIdx.x;
    int row = i >> 8;
    int g = i & 255;
    int g8 = g * 8;
    const float* src = p_w + (size_t)row * 2048;
    float4 a = *(const float4*)(src + g8);
    float4 bq = *(const float4*)(src + g8 + 4);
    float v[8] = {a.x, a.y, a.z, a.w, bq.x, bq.y, bq.z, bq.w};
    f16x8 vh;
    #pragma unroll
    for (int j = 0; j < 8; ++j)
        vh[j] = (h16)(v[j] * 4096.f);
    int permcol = (g & ~7) * 8 + ((g & 7) ^ (row & 7)) * 8;
    *(f16x8*)(wp + (size_t)row * 2048 + permcol) = vh;
}

__global__ __launch_bounds__(256) void concat_sb(const float* __restrict__ qs, const float* __restrict__ qb,
                                                 const float* __restrict__ ks, const float* __restrict__ kb,
                                                 const float* __restrict__ vs, const float* __restrict__ vb,
                                                 float* __restrict__ sc, float* __restrict__ bi) {
    int i = blockIdx.x * 256 + threadIdx.x;
    if (i >= 3072) return;
    if (i < 512)       { sc[i] = qs[i];        bi[i] = qb[i]; }
    else if (i < 1024) { sc[i] = ks[i - 512];  bi[i] = kb[i - 512]; }
    else               { sc[i] = vs[i - 1024]; bi[i] = vb[i - 1024]; }
}

// ---------------- MFMA GEMM qkv: BK=32 dbuf, raw s_barrier + counted vmcnt pipeline ----------------
// tile 128m x 32n x 4t, 4 waves; LDS 48KB -> 3 blocks/CU preserved.
__global__ __launch_bounds__(256, 3) void gemm_qkv_mfma(
        const h16* __restrict__ wp,     // [2][3072][512] swizzled (&3)
        const h16* __restrict__ sxT,    // [T][B][576][512] swizzled (&3)
        const float* __restrict__ sc,
        const float* __restrict__ bi,
        u32* __restrict__ qkvb32)       // [T*B][3072][18] u32 (= [..][9] u64)
{
    __shared__ h16 Ah[2][2][128][32];          // [buf][plane][row][k] 32 KB
    __shared__ h16 Bh[2][T_DIM][32][32];       // [buf][t][n][k] 16 KB

    // XCD-bijective remap (kept from R10; harmless)
    const int lin = blockIdx.x + 24 * (blockIdx.y + 18 * blockIdx.z);
    const int xcd = lin & 7, idx = lin >> 3;
    const int m0  = (3 * xcd + idx % 3) * 128;
    const int r2  = idx / 3;
    const int b   = r2 / 18;
    const int wq2 = r2 % 18;                   // n0 = wq2*32

    const int tid = threadIdx.x;
    const int lane = tid & 63;
    const int wv   = tid >> 6;
    const int l31  = lane & 31;
    const int lhi  = lane >> 5;

    const size_t APL = (size_t)3072 * 512;
    const size_t BPL = (size_t)B_DIM * N_DIM * 512;

    // staging sources: granule G = i*256+tid
    const h16* aS[4];
    #pragma unroll
    for (int i = 0; i < 4; ++i) {
        int G = i * 256 + tid;
        int pl = G >> 9, row = (G >> 2) & 127, gs = G & 3;
        aS[i] = wp + (size_t)pl * APL + (size_t)(m0 + row) * 512 + gs * 8;
    }
    const h16* bS[2];
    #pragma unroll
    for (int i = 0; i < 2; ++i) {
        int G = i * 256 + tid;
        int tt = G >> 7, row = (G >> 2) & 31, gs = G & 3;
        bS[i] = sxT + (size_t)tt * BPL + ((size_t)b * N_DIM + wq2 * 32 + row) * 512 + gs * 8;
    }

    f32x16 acc[T_DIM];
    #pragma unroll
    for (int t = 0; t < T_DIM; ++t) acc[t] = (f32x16)(0.f);

    // prologue: stage tile 0 into buf 0
    {
        char* aD = (char*)&Ah[0][0][0][0] + wv * 1024;
        char* bD = (char*)&Bh[0][0][0][0] + wv * 1024;
        gload16(aS[0], aD);
        gload16(aS[1], aD + 4096);
        gload16(aS[2], aD + 8192);
        gload16(aS[3], aD + 12288);
        gload16(bS[0], bD);
        gload16(bS[1], bD + 4096);
    }

    const int fsw = l31 & 3;
    for (int j = 0; j < 16; ++j) {
        const int cur = j & 1;
        __builtin_amdgcn_s_barrier();          // all waves done reading buf cur^1 (MFMA j-1)
        if (j < 15) {
            const int k0 = (j + 1) * 32;
            char* aD = (char*)&Ah[cur ^ 1][0][0][0] + wv * 1024;
            char* bD = (char*)&Bh[cur ^ 1][0][0][0] + wv * 1024;
            gload16(aS[0] + k0, aD);
            gload16(aS[1] + k0, aD + 4096);
            gload16(aS[2] + k0, aD + 8192);
            gload16(aS[3] + k0, aD + 12288);
            gload16(bS[0] + k0, bD);
            gload16(bS[1] + k0, bD + 4096);
            asm volatile("s_waitcnt vmcnt(6)" ::: "memory");   // tile j landed (in-order)
        } else {
            asm volatile("s_waitcnt vmcnt(0)" ::: "memory");   // final tile
        }
        __builtin_amdgcn_s_barrier();          // every wave's slice of tile j visible
        __builtin_amdgcn_sched_barrier(0);     // pin LDS reads below the barrier (rule #18)

        #pragma unroll
        for (int s = 0; s < 2; ++s) {
            const int g = ((s * 2 + lhi) ^ fsw) * 8;
            f16x8 a0 = *(const f16x8*)&Ah[cur][0][wv * 32 + l31][g];
            f16x8 a1 = *(const f16x8*)&Ah[cur][1][wv * 32 + l31][g];
            #pragma unroll
            for (int t = 0; t < T_DIM; ++t) {
                f16x8 bt = *(const f16x8*)&Bh[cur][t][l31][g];
                acc[t] = __builtin_amdgcn_mfma_f32_32x32x16_f16(a0, bt, acc[t], 0, 0, 0);
                acc[t] = __builtin_amdgcn_mfma_f32_32x32x16_f16(a1, bt, acc[t], 0, 0, 0);
            }
        }
    }
    __builtin_amdgcn_s_barrier();

    // epilogue: unscale, conv_bn, LIF over t, ballot-pack (u32 halves)
    const float inv = 0x1p-12f;
    #pragma unroll
    for (int r = 0; r < 16; ++r) {
        int row = m0 + wv * 32 + (r & 3) + 8 * (r >> 2) + 4 * lhi;
        float scv = sc[row], biv = bi[row];
        float mem = 0.f, spk = 0.f;
        #pragma unroll
        for (int t = 0; t < T_DIM; ++t) {
            float y = __fadd_rn(__fmul_rn(acc[t][r] * inv, scv), biv);
            mem = mem * 0.25f * (1.f - spk) + y;
            spk = (mem > 0.5f) ? 1.f : 0.f;
            u64 Bal = __ballot(spk > 0.f);
            u32 wrd = lhi ? (u32)(Bal >> 32) : (u32)Bal;
            if (l31 == 0)
                qkvb32[((size_t)(t * B_DIM + b) * 3072 + row) * 18 + wq2] = wrd;
        }
    }
}

// ---------------- Stage 4a: kv^T[e][d] = popcount over n of k&v (f16-exact ints) ----------------
__global__ __launch_bounds__(256) void kv_pop_kernel(const u64* __restrict__ bits,
                                                     h16* __restrict__ kvt) {  // [tbh][256 e][64 d]
    int tbh = blockIdx.x;
    int tb = tbh >> 3, h = tbh & 7;
    int e = threadIdx.x;
    __shared__ u64 kb[64][NW];
    const u64* kbase = bits + ((size_t)tb * 3072 + 512 + h * 64) * NW;
    const u64* vbase = bits + ((size_t)tb * 3072 + 1024 + h * 256) * NW;
    for (int i = threadIdx.x; i < 576; i += 256) kb[i / 9][i % 9] = kbase[i];
    __syncthreads();
    u64 vr[NW];
    #pragma unroll
    for (int w = 0; w < NW; ++w) vr[w] = vbase[(size_t)e * NW + w];
    h16* outp = kvt + (size_t)tbh * 16384 + (size_t)e * 64;
    for (int d0 = 0; d0 < 64; d0 += 4) {
        ushort4 pk;
        unsigned short* pp = (unsigned short*)&pk;
        #pragma unroll
        for (int j = 0; j < 4; ++j) {
            int scnt = 0;
            #pragma unroll
            for (int w = 0; w < NW; ++w) scnt += __popcll(kb[d0 + j][w] & vr[w]);
            union { h16 h; unsigned short u; } cv;
            cv.h = (h16)scnt;
            pp[j] = cv.u;
        }
        *(ushort4*)(outp + d0) = pk;
    }
}

// ---------------- Stage 4b+5: o^T = kv^T @ q^T via MFMA, LIF, dense transposed f16 spikes ----------------
__global__ __launch_bounds__(256, 2) void o_attn_mfma(const u64* __restrict__ qkvb,
                                                      const h16* __restrict__ kvt,
                                                      h16* __restrict__ soT) {
    const int nw = blockIdx.x;             // n-word: n0 = nw*64
    const int ec = blockIdx.y;             // e half (128)
    const int bh = blockIdx.z;
    const int b = bh >> 3, h = bh & 7;
    const int tid = threadIdx.x;
    const int lane = tid & 63, wv = tid >> 6, l31 = lane & 31, lhi = lane >> 5;

    __shared__ h16 kvs[128][64];           // 16 KB
    __shared__ __align__(16) u64 qbs[64];
    __shared__ h16 Tr[64][136];            // 17 KB transpose buffer

    const int st_row = tid >> 1;
    const int st_half = tid & 1;

    float mem0[16], spk0[16], mem1[16], spk1[16];
    #pragma unroll
    for (int r = 0; r < 16; ++r) { mem0[r] = 0.f; spk0[r] = 0.f; mem1[r] = 0.f; spk1[r] = 0.f; }

    for (int t = 0; t < T_DIM; ++t) {
        const int tb = t * B_DIM + b;
        __syncthreads();
        {
            const uint4* src = (const uint4*)(kvt + ((size_t)(tb * 8 + h) * 16384)
                                + (size_t)(ec * 128 + st_row) * 64 + st_half * 32);
            uint4 g0 = src[0], g1 = src[1], g2 = src[2], g3 = src[3];
            const int sw = st_row & 7;
            *(uint4*)&kvs[st_row][8 * ((st_half * 4 + 0) ^ sw)] = g0;
            *(uint4*)&kvs[st_row][8 * ((st_half * 4 + 1) ^ sw)] = g1;
            *(uint4*)&kvs[st_row][8 * ((st_half * 4 + 2) ^ sw)] = g2;
            *(uint4*)&kvs[st_row][8 * ((st_half * 4 + 3) ^ sw)] = g3;
        }
        if (tid < 64)
            qbs[tid] = qkvb[((size_t)tb * 3072 + h * 64 + tid) * NW + nw];
        __syncthreads();

        f32x16 acc0 = (f32x16)(0.f), acc1 = (f32x16)(0.f);
        const int er = wv * 32 + l31;
        const int esw = er & 7;
        const u32* qw32 = (const u32*)qbs;
        #pragma unroll
        for (int sub = 0; sub < 4; ++sub) {
            const int g = sub * 2 + lhi;
            f16x8 af = *(const f16x8*)&kvs[er][8 * (g ^ esw)];
            union { f16x8 v; unsigned short u[8]; } b0, b1;
            #pragma unroll
            for (int j = 0; j < 8; ++j) {
                const int d = sub * 16 + lhi * 8 + j;
                u32 w0 = qw32[d * 2 + 0];
                u32 w1 = qw32[d * 2 + 1];
                b0.u[j] = ((w0 >> l31) & 1u) ? (unsigned short)0x3C00 : (unsigned short)0;
                b1.u[j] = ((w1 >> l31) & 1u) ? (unsigned short)0x3C00 : (unsigned short)0;
            }
            acc0 = __builtin_amdgcn_mfma_f32_32x32x16_f16(af, b0.v, acc0, 0, 0, 0);
            acc1 = __builtin_amdgcn_mfma_f32_32x32x16_f16(af, b1.v, acc1, 0, 0, 0);
        }

        #pragma unroll
        for (int r = 0; r < 16; ++r) {
            mem0[r] = mem0[r] * 0.25f * (1.f - spk0[r]) + acc0[r] * 0.25f;
            spk0[r] = (mem0[r] > 0.5f) ? 1.f : 0.f;
            mem1[r] = mem1[r] * 0.25f * (1.f - spk1[r]) + acc1[r] * 0.25f;
            spk1[r] = (mem1[r] > 0.5f) ? 1.f : 0.f;
        }
        #pragma unroll
        for (int q = 0; q < 4; ++q) {
            ushort4 w0, w1;
            unsigned short* p0 = (unsigned short*)&w0;
            unsigned short* p1 = (unsigned short*)&w1;
            #pragma unroll
            for (int j = 0; j < 4; ++j) {
                union { h16 hh; unsigned short uu; } c0, c1;
                c0.hh = (h16)spk0[q * 4 + j];
                c1.hh = (h16)spk1[q * 4 + j];
                p0[j] = c0.uu;
                p1[j] = c1.uu;
            }
            int e = wv * 32 + 4 * lhi + 8 * q;
            *(ushort4*)&Tr[l31][e] = w0;
            *(ushort4*)&Tr[32 + l31][e] = w1;
        }
        __syncthreads();
        const size_t obase = ((size_t)tb * N_DIM + nw * 64) * CV_DIM + h * 256 + ec * 128;
        #pragma unroll
        for (int it = 0; it < 4; ++it) {
            int ch = it * 256 + tid;
            int n = ch >> 4, ge = ch & 15;
            uint4 v = *(const uint4*)&Tr[n][ge * 8];
            int gsw = (ge & 8) | ((ge & 7) ^ (n & 7));
            *(uint4*)(soT + obase + (size_t)n * CV_DIM + gsw * 8) = v;
        }
    }
}

// ---------------- MFMA GEMM p: hi-plane only, pure gload_lds staging, BK=64, 4 tb per block ----------------
__global__ __launch_bounds__(256, 3) void gemm_p_mfma(
        const h16* __restrict__ wp,     // [512][2048] swizzled (hi only, &7)
        const h16* __restrict__ soT,    // [TB][576][2048] swizzled (&7)
        const float* __restrict__ ps,
        const float* __restrict__ pb,
        float* __restrict__ out)        // [TB][512][576]
{
    __shared__ h16 Ah[128][64];                // 16 KB
    __shared__ h16 Bh[4][32][64];              // 16 KB

    const int tbq = blockIdx.z;                // 0..7 : tb = tbq*4 + tt
    const int m0  = blockIdx.x * 128;
    const int wq2 = blockIdx.y;                // 0..17: n0 = wq2*32
    const int tid = threadIdx.x;
    const int lane = tid & 63;
    const int wv   = tid >> 6;
    const int l31  = lane & 31;
    const int lhi  = lane >> 5;

    const h16* aB = wp + ((size_t)(m0 + (tid >> 3))) * 2048 + (tid & 7) * 8;
    const h16* bB = soT + ((size_t)(tbq * 4) * N_DIM + wq2 * 32 + (tid >> 3)) * 2048 + (tid & 7) * 8;
    char* ldsA = (char*)&Ah[0][0];
    char* ldsB = (char*)&Bh[0][0][0];
    const int woff = wv * 1024;

    f32x16 acc[4];
    #pragma unroll
    for (int tt = 0; tt < 4; ++tt) acc[tt] = (f32x16)(0.f);

    for (int k0 = 0; k0 < CV_DIM; k0 += 64) {
        #pragma unroll
        for (int i = 0; i < 4; ++i)
            gload16(aB + (size_t)(i * 32) * 2048 + k0,
                    ldsA + i * 4096 + woff);
        #pragma unroll
        for (int tt = 0; tt < 4; ++tt)
            gload16(bB + (size_t)tt * (N_DIM * CV_DIM) + k0,
                    ldsB + tt * 4096 + woff);
        __syncthreads();

        const int fsw = l31 & 7;
        #pragma unroll
        for (int s = 0; s < 4; ++s) {
            const int g = ((s * 2 + lhi) ^ fsw) * 8;
            f16x8 a0 = *(const f16x8*)&Ah[wv * 32 + l31][g];
            #pragma unroll
            for (int tt = 0; tt < 4; ++tt) {
                f16x8 bt = *(const f16x8*)&Bh[tt][l31][g];
                acc[tt] = __builtin_amdgcn_mfma_f32_32x32x16_f16(a0, bt, acc[tt], 0, 0, 0);
            }
        }
        __syncthreads();
    }

    const float inv = 0x1p-12f;
    #pragma unroll
    for (int r = 0; r < 16; ++r) {
        int row = m0 + wv * 32 + (r & 3) + 8 * (r >> 2) + 4 * lhi;
        float scv = ps[row], biv = pb[row];
        #pragma unroll
        for (int tt = 0; tt < 4; ++tt) {
            float y = __fadd_rn(__fmul_rn(acc[tt][r] * inv, scv), biv);
            out[(size_t)(tbq * 4 + tt) * (C_DIM * N_DIM) + (size_t)row * N_DIM + wq2 * 32 + l31] = y;
        }
    }
}

extern "C" void kernel_launch(void* const* d_in, const int* in_sizes, int n_in,
                              void* d_out, int out_size, void* d_ws, size_t ws_size,
                              hipStream_t stream) {
    const float* x    = (const float*)d_in[0];
    const float* pos  = (const float*)d_in[1];
    const float* q_w  = (const float*)d_in[2];
    const float* q_s  = (const float*)d_in[3];
    const float* q_b  = (const float*)d_in[4];
    const float* k_w  = (const float*)d_in[5];
    const float* k_s  = (const float*)d_in[6];
    const float* k_b  = (const float*)d_in[7];
    const float* v_w  = (const float*)d_in[8];
    const float* v_s  = (const float*)d_in[9];
    const float* v_b  = (const float*)d_in[10];
    const float* p_w  = (const float*)d_in[11];
    const float* p_s  = (const float*)d_in[12];
    const float* p_b  = (const float*)d_in[13];
    float* out = (float*)d_out;

    char* ws = (char*)d_ws;
    size_t off = 0;
    u64* qkvb = (u64*)(ws + off); off += 7077888;            // [T*B][3072][9]
    h16* kvt  = (h16*)(ws + off); off += 8388608;            // [T*B*8][256][64]
    h16* pw2  = (h16*)(ws + off); off += (size_t)2 * 512 * 2048 * 2;   // 4.19 MB (hi plane used)
    float* scc = (float*)(ws + off); off += 3072 * 4;
    float* bic = (float*)(ws + off); off += 3072 * 4;
    char* region = ws + off;
    h16* sxT  = (h16*)region;                                         // [T][B][576][512]
    h16* qkvw = (h16*)(region + (size_t)T_DIM * B_DIM * N_DIM * C_DIM * 2);  // [2][3072][512]
    h16* soT  = (h16*)region;                                         // [TB][576][2048]
    off += (size_t)TB_DIM * N_DIM * CV_DIM * 2;              // 75.5 MB region

    // 0) weight splits (swizzled) + scale/bias concat
    split_qkv<<<768, 256, 0, stream>>>(q_w, k_w, v_w, qkvw);
    split_p<<<512, 256, 0, stream>>>(p_w, pw2);
    concat_sb<<<12, 256, 0, stream>>>(q_s, q_b, k_s, k_b, v_s, v_b, scc, bic);

    // 1) LIF on x+pos -> transposed swizzled f16 spikes
    dim3 gl(C_DIM / 64, N_DIM / 64, B_DIM);   // (8,9,8)
    lif_x_T<<<gl, 256, 0, stream>>>(x, pos, sxT);

    // 2) fused q/k/v MFMA GEMM + LIF + pack (counted-vmcnt pipeline)
    dim3 gq(3072 / 128, 18, B_DIM);    // (24,18,8) -> 3456 wgs, XCD-remapped in-kernel
    gemm_qkv_mfma<<<gq, 256, 0, stream>>>(qkvw, sxT, scc, bic, (u32*)qkvb);

    // 3) attention: popcount kv (f16 ints), then MFMA o + LIF -> dense transposed spikes
    kv_pop_kernel<<<TB_DIM * 8, 256, 0, stream>>>(qkvb, kvt);
    dim3 go(NW, 2, B_DIM * 8);         // (9,2,64)
    o_attn_mfma<<<go, 256, 0, stream>>>(qkvb, kvt, soT);

    // 4) output projection (MFMA, hi-plane only)
    dim3 gp(C_DIM / 128, 18, TB_DIM / 4);   // (4,18,8)
    gemm_p_mfma<<<gp, 256, 0, stream>>>(pw2, soT, p_s, p_b, out);
}

// Round 12
// 239.947 us; speedup vs baseline: 1.0724x; 1.0724x over previous
//
#include <hip/hip_runtime.h>
#include <cstdint>

#define T_DIM 4
#define B_DIM 8
#define C_DIM 512
#define N_DIM 576
#define CV_DIM 2048
#define TB_DIM 32
#define NW 9              // u64 words per row of N=576

typedef unsigned long long u64;
typedef unsigned char u8;
typedef uint32_t u32;
typedef _Float16 h16;
typedef __attribute__((ext_vector_type(8))) _Float16 f16x8;
typedef __attribute__((ext_vector_type(16))) float f32x16;

// async global->LDS, 16B per lane; lds ptr must be wave-uniform chunk base
__device__ __forceinline__ void gload16(const void* gp, void* lp) {
    __builtin_amdgcn_global_load_lds(
        (const __attribute__((address_space(1))) void*)gp,
        (__attribute__((address_space(3))) void*)lp, 16, 0, 0);
}

// ---------------- Stage 1: LIF over (x + pos) -> dense f16 spikes, TRANSPOSED [t][b][n][c] ----------------
// c-granules (8 h16 = 16B) XOR-swizzled by (n&7) within each 64-c chunk (matches gemm frag reads).
__global__ __launch_bounds__(256) void lif_x_T(const float* __restrict__ x,
                                               const float* __restrict__ pos,
                                               h16* __restrict__ sxT) {
    const int ct = blockIdx.x, nt = blockIdx.y, b = blockIdx.z;
    const int c0 = ct * 64, n0 = nt * 64;
    __shared__ h16 T[64][64];              // [n][c] 8 KB
    const int tid = threadIdx.x;
    const int n_l = tid & 63, cg = tid >> 6;
    const int row = tid >> 2, q = tid & 3;

    float pv[16], mem[16], spk[16];
    #pragma unroll
    for (int ii = 0; ii < 16; ++ii) {
        pv[ii] = pos[(c0 + cg * 16 + ii) * N_DIM + n0 + n_l];
        mem[ii] = 0.f; spk[ii] = 0.f;
    }
    for (int t = 0; t < T_DIM; ++t) {
        #pragma unroll
        for (int ii = 0; ii < 16; ++ii) {
            float xt = x[((size_t)(t * B_DIM + b) * C_DIM + c0 + cg * 16 + ii) * N_DIM + n0 + n_l] + pv[ii];
            mem[ii] = mem[ii] * 0.25f * (1.f - spk[ii]) + xt;
            spk[ii] = (mem[ii] > 0.5f) ? 1.f : 0.f;
            T[n_l][cg * 16 + ii] = (h16)spk[ii];
        }
        __syncthreads();
        {
            h16* dst = sxT + ((size_t)(t * B_DIM + b) * N_DIM + n0 + row) * C_DIM + c0;
            const int f = row & 7;
            #pragma unroll
            for (int e = 0; e < 2; ++e) {
                int gl = q + e * 4;
                uint4 v = *(const uint4*)&T[row][gl * 8];
                *(uint4*)(dst + (gl ^ f) * 8) = v;
            }
        }
        __syncthreads();
    }
}

// ---------------- Merged prep: qkv split (&7 swz) + p split (hi, &7 swz) + scale/bias concat ----------------
__global__ __launch_bounds__(256) void prep_weights(
        const float* __restrict__ q_w, const float* __restrict__ k_w, const float* __restrict__ v_w,
        const float* __restrict__ p_w,
        const float* __restrict__ qs, const float* __restrict__ qb,
        const float* __restrict__ ks, const float* __restrict__ kb,
        const float* __restrict__ vs, const float* __restrict__ vb,
        h16* __restrict__ qkvw,        // [2][3072][512]
        h16* __restrict__ pw,          // [512][2048] hi only
        float* __restrict__ sc, float* __restrict__ bi) {
    const int bid = blockIdx.x;
    const int tid = threadIdx.x;
    if (bid < 768) {
        // qkv split: 196608 granules
        int i = bid * 256 + tid;
        int row = i >> 6;
        int g = i & 63;
        int g8 = g * 8;
        const float* src = (row < 512) ? q_w + (size_t)row * 512
                         : (row < 1024) ? k_w + (size_t)(row - 512) * 512
                                        : v_w + (size_t)(row - 1024) * 512;
        float4 a = *(const float4*)(src + g8);
        float4 bq = *(const float4*)(src + g8 + 4);
        float v[8] = {a.x, a.y, a.z, a.w, bq.x, bq.y, bq.z, bq.w};
        f16x8 vh, vl;
        #pragma unroll
        for (int j = 0; j < 8; ++j) {
            float w = v[j] * 4096.f;
            h16 h1 = (h16)w;
            vh[j] = h1;
            vl[j] = (h16)(w - (float)h1);
        }
        int permcol = (g & ~7) * 8 + ((g & 7) ^ (row & 7)) * 8;
        *(f16x8*)(qkvw + (size_t)row * 512 + permcol) = vh;
        *(f16x8*)(qkvw + (size_t)3072 * 512 + (size_t)row * 512 + permcol) = vl;
    } else if (bid < 1280) {
        // p split (hi only): 131072 granules
        int i = (bid - 768) * 256 + tid;
        int row = i >> 8;
        int g = i & 255;
        int g8 = g * 8;
        const float* src = p_w + (size_t)row * 2048;
        float4 a = *(const float4*)(src + g8);
        float4 bq = *(const float4*)(src + g8 + 4);
        float v[8] = {a.x, a.y, a.z, a.w, bq.x, bq.y, bq.z, bq.w};
        f16x8 vh;
        #pragma unroll
        for (int j = 0; j < 8; ++j)
            vh[j] = (h16)(v[j] * 4096.f);
        int permcol = (g & ~7) * 8 + ((g & 7) ^ (row & 7)) * 8;
        *(f16x8*)(pw + (size_t)row * 2048 + permcol) = vh;
    } else {
        // concat scale/bias: 3072 elements over 12 blocks
        int i = (bid - 1280) * 256 + tid;
        if (i < 512)       { sc[i] = qs[i];        bi[i] = qb[i]; }
        else if (i < 1024) { sc[i] = ks[i - 512];  bi[i] = kb[i - 512]; }
        else               { sc[i] = vs[i - 1024]; bi[i] = vb[i - 1024]; }
    }
}

// ---------------- MFMA GEMM qkv: global_load_lds staging, BK=64, 32-col tiles, LIF+pack ----------------
// XCD-bijective swizzle: each XCD owns 3 m-blocks -> A slices stay L2-resident.
__global__ __launch_bounds__(256, 3) void gemm_qkv_mfma(
        const h16* __restrict__ wp,     // [2][3072][512] swizzled
        const h16* __restrict__ sxT,    // [T][B][576][512] swizzled
        const float* __restrict__ sc,
        const float* __restrict__ bi,
        u32* __restrict__ qkvb32)       // [T*B][3072][18] u32 (= [..][9] u64)
{
    __shared__ h16 Ah[2][128][64];             // 32 KB
    __shared__ h16 Bh[T_DIM][32][64];          // 16 KB

    const int lin = blockIdx.x + 24 * (blockIdx.y + 18 * blockIdx.z);
    const int xcd = lin & 7, idx = lin >> 3;           // idx in [0,432)
    const int m0  = (3 * xcd + idx % 3) * 128;
    const int r2  = idx / 3;                           // [0,144)
    const int b   = r2 / 18;
    const int wq2 = r2 % 18;                           // n0 = wq2*32

    const int tid = threadIdx.x;
    const int lane = tid & 63;
    const int wv   = tid >> 6;
    const int l31  = lane & 31;
    const int lhi  = lane >> 5;

    const h16* aB = wp + ((size_t)(m0 + (tid >> 3))) * 512 + (tid & 7) * 8;
    const h16* bB = sxT + ((size_t)b * N_DIM + wq2 * 32 + (tid >> 3)) * 512 + (tid & 7) * 8;
    char* ldsA = (char*)&Ah[0][0][0];
    char* ldsB = (char*)&Bh[0][0][0];
    const int woff = wv * 1024;

    f32x16 acc[T_DIM];
    #pragma unroll
    for (int t = 0; t < T_DIM; ++t) acc[t] = (f32x16)(0.f);

    for (int k0 = 0; k0 < 512; k0 += 64) {
        #pragma unroll
        for (int i = 0; i < 8; ++i)
            gload16(aB + ((size_t)(i >> 2) * 3072 + (i & 3) * 32) * 512 + k0,
                    ldsA + i * 4096 + woff);
        #pragma unroll
        for (int i = 0; i < 4; ++i)
            gload16(bB + (size_t)i * (B_DIM * N_DIM) * 512 + k0,
                    ldsB + i * 4096 + woff);
        __syncthreads();

        const int fsw = l31 & 7;
        #pragma unroll
        for (int s = 0; s < 4; ++s) {
            const int g = ((s * 2 + lhi) ^ fsw) * 8;
            f16x8 a0 = *(const f16x8*)&Ah[0][wv * 32 + l31][g];
            f16x8 a1 = *(const f16x8*)&Ah[1][wv * 32 + l31][g];
            #pragma unroll
            for (int t = 0; t < T_DIM; ++t) {
                f16x8 bt = *(const f16x8*)&Bh[t][l31][g];
                acc[t] = __builtin_amdgcn_mfma_f32_32x32x16_f16(a0, bt, acc[t], 0, 0, 0);
                acc[t] = __builtin_amdgcn_mfma_f32_32x32x16_f16(a1, bt, acc[t], 0, 0, 0);
            }
        }
        __syncthreads();
    }

    const float inv = 0x1p-12f;
    #pragma unroll
    for (int r = 0; r < 16; ++r) {
        int row = m0 + wv * 32 + (r & 3) + 8 * (r >> 2) + 4 * lhi;
        float scv = sc[row], biv = bi[row];
        float mem = 0.f, spk = 0.f;
        #pragma unroll
        for (int t = 0; t < T_DIM; ++t) {
            float y = __fadd_rn(__fmul_rn(acc[t][r] * inv, scv), biv);
            mem = mem * 0.25f * (1.f - spk) + y;
            spk = (mem > 0.5f) ? 1.f : 0.f;
            u64 Bal = __ballot(spk > 0.f);
            u32 wrd = lhi ? (u32)(Bal >> 32) : (u32)Bal;
            if (l31 == 0)
                qkvb32[((size_t)(t * B_DIM + b) * 3072 + row) * 18 + wq2] = wrd;
        }
    }
}

// ---------------- Stage 4a: kv^T[e][d] = popcount over n of k&v (f16-exact ints) ----------------
__global__ __launch_bounds__(256) void kv_pop_kernel(const u64* __restrict__ bits,
                                                     h16* __restrict__ kvt) {  // [tbh][256 e][64 d]
    int tbh = blockIdx.x;
    int tb = tbh >> 3, h = tbh & 7;
    int e = threadIdx.x;
    __shared__ u64 kb[64][NW];
    const u64* kbase = bits + ((size_t)tb * 3072 + 512 + h * 64) * NW;
    const u64* vbase = bits + ((size_t)tb * 3072 + 1024 + h * 256) * NW;
    for (int i = threadIdx.x; i < 576; i += 256) kb[i / 9][i % 9] = kbase[i];
    __syncthreads();
    u64 vr[NW];
    #pragma unroll
    for (int w = 0; w < NW; ++w) vr[w] = vbase[(size_t)e * NW + w];
    h16* outp = kvt + (size_t)tbh * 16384 + (size_t)e * 64;
    for (int d0 = 0; d0 < 64; d0 += 4) {
        ushort4 pk;
        unsigned short* pp = (unsigned short*)&pk;
        #pragma unroll
        for (int j = 0; j < 4; ++j) {
            int scnt = 0;
            #pragma unroll
            for (int w = 0; w < NW; ++w) scnt += __popcll(kb[d0 + j][w] & vr[w]);
            union { h16 h; unsigned short u; } cv;
            cv.h = (h16)scnt;
            pp[j] = cv.u;
        }
        *(ushort4*)(outp + d0) = pk;
    }
}

// ---------------- Stage 4b+5: o^T = kv^T @ q^T via MFMA, LIF, dense transposed f16 spikes ----------------
__global__ __launch_bounds__(256, 2) void o_attn_mfma(const u64* __restrict__ qkvb,
                                                      const h16* __restrict__ kvt,
                                                      h16* __restrict__ soT) {
    const int nw = blockIdx.x;             // n-word: n0 = nw*64
    const int ec = blockIdx.y;             // e half (128)
    const int bh = blockIdx.z;
    const int b = bh >> 3, h = bh & 7;
    const int tid = threadIdx.x;
    const int lane = tid & 63, wv = tid >> 6, l31 = lane & 31, lhi = lane >> 5;

    __shared__ h16 kvs[128][64];           // 16 KB
    __shared__ __align__(16) u64 qbs[64];
    __shared__ h16 Tr[64][136];            // 17 KB transpose buffer

    const int st_row = tid >> 1;
    const int st_half = tid & 1;

    float mem0[16], spk0[16], mem1[16], spk1[16];
    #pragma unroll
    for (int r = 0; r < 16; ++r) { mem0[r] = 0.f; spk0[r] = 0.f; mem1[r] = 0.f; spk1[r] = 0.f; }

    for (int t = 0; t < T_DIM; ++t) {
        const int tb = t * B_DIM + b;
        __syncthreads();
        {
            const uint4* src = (const uint4*)(kvt + ((size_t)(tb * 8 + h) * 16384)
                                + (size_t)(ec * 128 + st_row) * 64 + st_half * 32);
            uint4 g0 = src[0], g1 = src[1], g2 = src[2], g3 = src[3];
            const int sw = st_row & 7;
            *(uint4*)&kvs[st_row][8 * ((st_half * 4 + 0) ^ sw)] = g0;
            *(uint4*)&kvs[st_row][8 * ((st_half * 4 + 1) ^ sw)] = g1;
            *(uint4*)&kvs[st_row][8 * ((st_half * 4 + 2) ^ sw)] = g2;
            *(uint4*)&kvs[st_row][8 * ((st_half * 4 + 3) ^ sw)] = g3;
        }
        if (tid < 64)
            qbs[tid] = qkvb[((size_t)tb * 3072 + h * 64 + tid) * NW + nw];
        __syncthreads();

        f32x16 acc0 = (f32x16)(0.f), acc1 = (f32x16)(0.f);
        const int er = wv * 32 + l31;
        const int esw = er & 7;
        const u32* qw32 = (const u32*)qbs;
        #pragma unroll
        for (int sub = 0; sub < 4; ++sub) {
            const int g = sub * 2 + lhi;
            f16x8 af = *(const f16x8*)&kvs[er][8 * (g ^ esw)];
            union { f16x8 v; unsigned short u[8]; } b0, b1;
            #pragma unroll
            for (int j = 0; j < 8; ++j) {
                const int d = sub * 16 + lhi * 8 + j;
                u32 w0 = qw32[d * 2 + 0];
                u32 w1 = qw32[d * 2 + 1];
                b0.u[j] = ((w0 >> l31) & 1u) ? (unsigned short)0x3C00 : (unsigned short)0;
                b1.u[j] = ((w1 >> l31) & 1u) ? (unsigned short)0x3C00 : (unsigned short)0;
            }
            acc0 = __builtin_amdgcn_mfma_f32_32x32x16_f16(af, b0.v, acc0, 0, 0, 0);
            acc1 = __builtin_amdgcn_mfma_f32_32x32x16_f16(af, b1.v, acc1, 0, 0, 0);
        }

        #pragma unroll
        for (int r = 0; r < 16; ++r) {
            mem0[r] = mem0[r] * 0.25f * (1.f - spk0[r]) + acc0[r] * 0.25f;
            spk0[r] = (mem0[r] > 0.5f) ? 1.f : 0.f;
            mem1[r] = mem1[r] * 0.25f * (1.f - spk1[r]) + acc1[r] * 0.25f;
            spk1[r] = (mem1[r] > 0.5f) ? 1.f : 0.f;
        }
        #pragma unroll
        for (int q = 0; q < 4; ++q) {
            ushort4 w0, w1;
            unsigned short* p0 = (unsigned short*)&w0;
            unsigned short* p1 = (unsigned short*)&w1;
            #pragma unroll
            for (int j = 0; j < 4; ++j) {
                union { h16 hh; unsigned short uu; } c0, c1;
                c0.hh = (h16)spk0[q * 4 + j];
                c1.hh = (h16)spk1[q * 4 + j];
                p0[j] = c0.uu;
                p1[j] = c1.uu;
            }
            int e = wv * 32 + 4 * lhi + 8 * q;
            *(ushort4*)&Tr[l31][e] = w0;
            *(ushort4*)&Tr[32 + l31][e] = w1;
        }
        __syncthreads();
        const size_t obase = ((size_t)tb * N_DIM + nw * 64) * CV_DIM + h * 256 + ec * 128;
        #pragma unroll
        for (int it = 0; it < 4; ++it) {
            int ch = it * 256 + tid;
            int n = ch >> 4, ge = ch & 15;
            uint4 v = *(const uint4*)&Tr[n][ge * 8];
            int gsw = (ge & 8) | ((ge & 7) ^ (n & 7));
            *(uint4*)(soT + obase + (size_t)n * CV_DIM + gsw * 8) = v;
        }
    }
}

// ---------------- MFMA GEMM p: hi-plane only, pure gload_lds staging, BK=64, 4 tb per block ----------------
__global__ __launch_bounds__(256, 3) void gemm_p_mfma(
        const h16* __restrict__ wp,     // [512][2048] swizzled (hi only)
        const h16* __restrict__ soT,    // [TB][576][2048] swizzled
        const float* __restrict__ ps,
        const float* __restrict__ pb,
        float* __restrict__ out)        // [TB][512][576]
{
    __shared__ h16 Ah[128][64];                // 16 KB
    __shared__ h16 Bh[4][32][64];              // 16 KB

    const int tbq = blockIdx.z;                // 0..7 : tb = tbq*4 + tt
    const int m0  = blockIdx.x * 128;
    const int wq2 = blockIdx.y;                // 0..17: n0 = wq2*32
    const int tid = threadIdx.x;
    const int lane = tid & 63;
    const int wv   = tid >> 6;
    const int l31  = lane & 31;
    const int lhi  = lane >> 5;

    const h16* aB = wp + ((size_t)(m0 + (tid >> 3))) * 2048 + (tid & 7) * 8;
    const h16* bB = soT + ((size_t)(tbq * 4) * N_DIM + wq2 * 32 + (tid >> 3)) * 2048 + (tid & 7) * 8;
    char* ldsA = (char*)&Ah[0][0];
    char* ldsB = (char*)&Bh[0][0][0];
    const int woff = wv * 1024;

    f32x16 acc[4];
    #pragma unroll
    for (int tt = 0; tt < 4; ++tt) acc[tt] = (f32x16)(0.f);

    for (int k0 = 0; k0 < CV_DIM; k0 += 64) {
        #pragma unroll
        for (int i = 0; i < 4; ++i)
            gload16(aB + (size_t)(i * 32) * 2048 + k0,
                    ldsA + i * 4096 + woff);
        #pragma unroll
        for (int tt = 0; tt < 4; ++tt)
            gload16(bB + (size_t)tt * (N_DIM * CV_DIM) + k0,
                    ldsB + tt * 4096 + woff);
        __syncthreads();

        const int fsw = l31 & 7;
        #pragma unroll
        for (int s = 0; s < 4; ++s) {
            const int g = ((s * 2 + lhi) ^ fsw) * 8;
            f16x8 a0 = *(const f16x8*)&Ah[wv * 32 + l31][g];
            #pragma unroll
            for (int tt = 0; tt < 4; ++tt) {
                f16x8 bt = *(const f16x8*)&Bh[tt][l31][g];
                acc[tt] = __builtin_amdgcn_mfma_f32_32x32x16_f16(a0, bt, acc[tt], 0, 0, 0);
            }
        }
        __syncthreads();
    }

    const float inv = 0x1p-12f;
    #pragma unroll
    for (int r = 0; r < 16; ++r) {
        int row = m0 + wv * 32 + (r & 3) + 8 * (r >> 2) + 4 * lhi;
        float scv = ps[row], biv = pb[row];
        #pragma unroll
        for (int tt = 0; tt < 4; ++tt) {
            float y = __fadd_rn(__fmul_rn(acc[tt][r] * inv, scv), biv);
            out[(size_t)(tbq * 4 + tt) * (C_DIM * N_DIM) + (size_t)row * N_DIM + wq2 * 32 + l31] = y;
        }
    }
}

extern "C" void kernel_launch(void* const* d_in, const int* in_sizes, int n_in,
                              void* d_out, int out_size, void* d_ws, size_t ws_size,
                              hipStream_t stream) {
    const float* x    = (const float*)d_in[0];
    const float* pos  = (const float*)d_in[1];
    const float* q_w  = (const float*)d_in[2];
    const float* q_s  = (const float*)d_in[3];
    const float* q_b  = (const float*)d_in[4];
    const float* k_w  = (const float*)d_in[5];
    const float* k_s  = (const float*)d_in[6];
    const float* k_b  = (const float*)d_in[7];
    const float* v_w  = (const float*)d_in[8];
    const float* v_s  = (const float*)d_in[9];
    const float* v_b  = (const float*)d_in[10];
    const float* p_w  = (const float*)d_in[11];
    const float* p_s  = (const float*)d_in[12];
    const float* p_b  = (const float*)d_in[13];
    float* out = (float*)d_out;

    char* ws = (char*)d_ws;
    size_t off = 0;
    u64* qkvb = (u64*)(ws + off); off += 7077888;            // [T*B][3072][9]
    h16* kvt  = (h16*)(ws + off); off += 8388608;            // [T*B*8][256][64]
    h16* pw2  = (h16*)(ws + off); off += (size_t)2 * 512 * 2048 * 2;   // 4.19 MB (hi plane used)
    float* scc = (float*)(ws + off); off += 3072 * 4;
    float* bic = (float*)(ws + off); off += 3072 * 4;
    char* region = ws + off;
    h16* sxT  = (h16*)region;                                         // [T][B][576][512]
    h16* qkvw = (h16*)(region + (size_t)T_DIM * B_DIM * N_DIM * C_DIM * 2);  // [2][3072][512]
    h16* soT  = (h16*)region;                                         // [TB][576][2048]
    off += (size_t)TB_DIM * N_DIM * CV_DIM * 2;              // 75.5 MB region

    // 0) merged weight prep (qkv split + p split + scale/bias concat)
    prep_weights<<<1292, 256, 0, stream>>>(q_w, k_w, v_w, p_w,
                                           q_s, q_b, k_s, k_b, v_s, v_b,
                                           qkvw, pw2, scc, bic);

    // 1) LIF on x+pos -> transposed swizzled f16 spikes
    dim3 gl(C_DIM / 64, N_DIM / 64, B_DIM);   // (8,9,8)
    lif_x_T<<<gl, 256, 0, stream>>>(x, pos, sxT);

    // 2) fused q/k/v MFMA GEMM + LIF + pack (XCD-swizzled)
    dim3 gq(3072 / 128, 18, B_DIM);    // (24,18,8) -> 3456 wgs, bijectively remapped in-kernel
    gemm_qkv_mfma<<<gq, 256, 0, stream>>>(qkvw, sxT, scc, bic, (u32*)qkvb);

    // 3) attention: popcount kv (f16 ints), then MFMA o + LIF -> dense transposed spikes
    kv_pop_kernel<<<TB_DIM * 8, 256, 0, stream>>>(qkvb, kvt);
    dim3 go(NW, 2, B_DIM * 8);         // (9,2,64)
    o_attn_mfma<<<go, 256, 0, stream>>>(qkvb, kvt, soT);

    // 4) output projection (MFMA, hi-plane only)
    dim3 gp(C_DIM / 128, 18, TB_DIM / 4);   // (4,18,8)
    gemm_p_mfma<<<gp, 256, 0, stream>>>(pw2, soT, p_s, p_b, out);
}